// Round 1
// 118.953 us; speedup vs baseline: 1.0024x; 1.0024x over previous
//
#include <hip/hip_runtime.h>
#include <math.h>

#define NBULK 62
#define SB    72   // padded LDS row stride (bf16) for norm-path E/St tiles

typedef __attribute__((ext_vector_type(8))) short bf8_t;    // 8 x bf16
typedef __attribute__((ext_vector_type(4))) float f4_t;     // 4 x fp32
typedef __attribute__((ext_vector_type(16))) float f16v_t;  // 16 x fp32

#define MFMA16(a, b, c) __builtin_amdgcn_mfma_f32_16x16x32_bf16((a), (b), (c), 0, 0, 0)
#define MFMA32(a, b, c) __builtin_amdgcn_mfma_f32_32x32x16_bf16((a), (b), (c), 0, 0, 0)

__device__ __forceinline__ unsigned short f2bf(float f) {
    unsigned int u = __float_as_uint(f);
    return (unsigned short)((u + 0x7FFFu + ((u >> 16) & 1u)) >> 16);
}
__device__ __forceinline__ float bf2f(unsigned short h) {
    return __uint_as_float(((unsigned int)h) << 16);
}
// pack 2 f32 -> 2 bf16 in one dword (RNE), single instruction
__device__ __forceinline__ unsigned cvtpk(float lo, float hi) {
    unsigned r;
    asm("v_cvt_pk_bf16_f32 %0, %1, %2" : "=v"(r) : "v"(lo), "v"(hi));
    return r;
}

// async global->LDS, 16B per lane; lptr must be wave-uniform (HW adds lane*16)
__device__ __forceinline__ void gload16(const void* g, void* l) {
    __builtin_amdgcn_global_load_lds(
        (const __attribute__((address_space(1))) unsigned int*)g,
        (__attribute__((address_space(3))) unsigned int*)l, 16, 0, 0);
}

// ---- ws layout ----
// floats: [0]=psisum [1]=lsf [2]=lsb ; E_fwd at float 1024, E_bwd at float 6144
// bytes:  BT (swizzled, 62*16KB) at 45056 ; MR (swizzled) at 1060864
#define WS_E_OFF   1024
#define WS_B_OFF   6144
#define WS_BT_OFF  45056
#define WS_MR_OFF  1060864

// swizzled offset of element (row n, col k) inside a 128x64 bf16 tile:
//   n*64 + ((k>>3 ^ (n&7))<<3 | (k&7))
// consumers read 8-contig k-group g at: n*64 + ((g ^ (n&7))<<3)

extern "C" __global__ __launch_bounds__(256)
void mps_precompute(const float* __restrict__ bulkG,
                    unsigned short* __restrict__ BTg,
                    unsigned short* __restrict__ MRg,
                    float* __restrict__ wsF)
{
    __shared__ unsigned short BTl[8192];
    __shared__ unsigned short MRl[8192];
    const int s = blockIdx.x, tid = threadIdx.x;
    if (s == 0 && tid == 0) {   // replaces hipMemsetAsync (one fewer dispatch)
        wsF[0] = 0.f; wsF[1] = 0.f; wsF[2] = 0.f; wsF[3] = 0.f;
    }
    const float4* src = (const float4*)(bulkG + (size_t)s * 8192);
    for (int c = 0; c < 8; ++c) {
        int idx = tid + c * 256;            // 0..2047
        float4 v = src[idx];
        int f  = idx * 4;
        int kk = f >> 7;                    // 0..63
        int p  = (f >> 6) & 1;
        int j  = f & 63;                    // multiple of 4
        unsigned short b0 = f2bf(v.x), b1 = f2bf(v.y), b2 = f2bf(v.z), b3 = f2bf(v.w);
        // MR row n = p*64+kk holds M_p[kk][:]
        int n = p * 64 + kk;
        int off = n * 64 + (((j >> 3) ^ (n & 7)) << 3) + (j & 7);
        MRl[off + 0] = b0; MRl[off + 1] = b1; MRl[off + 2] = b2; MRl[off + 3] = b3;
        // BT rows n' = p*64 + j.. hold columns of M_p
        unsigned short bb[4] = {b0, b1, b2, b3};
        #pragma unroll
        for (int t2 = 0; t2 < 4; ++t2) {
            int n2 = p * 64 + j + t2;
            BTl[n2 * 64 + (((kk >> 3) ^ (n2 & 7)) << 3) + (kk & 7)] = bb[t2];
        }
    }
    __syncthreads();
    const uint4* bt4 = (const uint4*)BTl;
    const uint4* mr4 = (const uint4*)MRl;
    uint4* btg = (uint4*)(BTg + (size_t)s * 8192);
    uint4* mrg = (uint4*)(MRg + (size_t)s * 8192);
    for (int c = 0; c < 4; ++c) {
        int idx = tid + c * 256;
        btg[idx] = bt4[idx];
        mrg[idx] = mr4[idx];
    }
}

// ===================== psi chain step (one wave, 32 samples) =====================
// env (LDS, [32 rows=samples][64 bf16], 16B-groups XOR-swizzled by sample&7) is the
// MFMA B operand; A = BT tile rows (M^T) read straight from global into registers.
// C layout (32x32x16): col = sample = lane&31, row = (reg&3)+8*(reg>>2)+4*(lane>>5).
__device__ __forceinline__ void psi_phase(
    uint4 (&R)[16], int tt, unsigned short* env, const char* BTb,
    const int (&off)[4], unsigned selLo, unsigned selHi,
    int s, int hi, int e7, const f16v_t& Z)
{
    // B fragments: lane (hi,s) needs k = ks*16 + hi*8 + jj  -> logical group ks*2+hi
    bf8_t benv[4];
    #pragma unroll
    for (int ks = 0; ks < 4; ++ks)
        benv[ks] = *(const bf8_t*)((const char*)env + s * 128 + (((ks * 2 + hi) ^ e7) << 4));
    // branch-select bit for this site (config column tt+1) of this lane's sample
    unsigned sbit = (tt + 1 < 32) ? (selLo >> (tt + 1)) : (selHi >> (tt - 31));
    const bool takeB = (sbit & 1u) != 0u;
    #pragma unroll
    for (int jt = 0; jt < 2; ++jt) {            // output bond tile (rows jt*32..+31)
        f16v_t a0 = Z, a1 = Z;                  // p=0 / p=1 branch accumulators
        #pragma unroll
        for (int ks = 0; ks < 4; ++ks) {
            a0 = MFMA32(*(const bf8_t*)&R[jt * 4 + ks],     benv[ks], a0);
            a1 = MFMA32(*(const bf8_t*)&R[8 + jt * 4 + ks], benv[ks], a1);
        }
        // select branch per sample (lane-uniform bool), pack bf16, write env'
        #pragma unroll
        for (int b = 0; b < 4; ++b) {           // rows jt*32 + 8b + 4hi + {0..3}
            float v0 = takeB ? a1[4 * b + 0] : a0[4 * b + 0];
            float v1 = takeB ? a1[4 * b + 1] : a0[4 * b + 1];
            float v2 = takeB ? a1[4 * b + 2] : a0[4 * b + 2];
            float v3 = takeB ? a1[4 * b + 3] : a0[4 * b + 3];
            uint2 w;
            w.x = cvtpk(v0, v1);
            w.y = cvtpk(v2, v3);
            *(uint2*)((char*)env + s * 128 + (((jt * 4 + b) ^ e7) << 4) + hi * 8) = w;
        }
    }
    // prefetch tile tt+2 into the just-consumed register set (full phase of slack;
    // no barriers anywhere -> compiler emits counted vmcnt, never a drain)
    if (tt + 2 < NBULK) {
        const char* tb = BTb + (size_t)(tt + 2) * 16384;
        #pragma unroll
        for (int p = 0; p < 2; ++p)
            #pragma unroll
            for (int jt = 0; jt < 2; ++jt)
                #pragma unroll
                for (int ks = 0; ks < 4; ++ks)
                    R[p * 8 + jt * 4 + ks] =
                        *(const uint4*)(tb + p * 8192 + jt * 4096 + off[ks]);
    }
}

extern "C" __global__ __launch_bounds__(256)
void mps_main(const int* __restrict__ cfgG, const float* __restrict__ leftG,
              const float* __restrict__ rightG, float* __restrict__ wsF,
              const unsigned short* __restrict__ BTg,
              const unsigned short* __restrict__ MRg)
{
    extern __shared__ char smem[];
    unsigned short* smem16 = (unsigned short*)smem;
    const int tid  = threadIdx.x;
    const int bid  = blockIdx.x;
    const int wv   = tid >> 6;
    const int lane = tid & 63;

    if (bid >= 2) {
        // ========== psi: 64 samples/block; waves 0,1 = independent 32-sample chains,
        // barrier-free; waves 2,3 exit (no __syncthreads anywhere in this path) ==========
        if (wv >= 2) return;
        const int s  = lane & 31;    // sample within chain
        const int hi = lane >> 5;
        const int e7 = lane & 7;
        unsigned short* env = smem16 + wv * 2048;     // 4KB swizzled env tile per wave
        const int s0 = (bid - 2) * 64 + wv * 32;

        // per-lane A-frag byte offsets within a (p,jt) 8KB sub-tile (swizzle folded in)
        int off[4];
        #pragma unroll
        for (int ks = 0; ks < 4; ++ks)
            off[ks] = s * 128 + (((ks * 2 + hi) ^ e7) << 4);

        const char* BTb = (const char*)BTg;
        uint4 ra[16], rb[16];
        #pragma unroll
        for (int p = 0; p < 2; ++p)
            #pragma unroll
            for (int jt = 0; jt < 2; ++jt)
                #pragma unroll
                for (int ks = 0; ks < 4; ++ks) {
                    ra[p * 8 + jt * 4 + ks] = *(const uint4*)(BTb + p * 8192 + jt * 4096 + off[ks]);
                    rb[p * 8 + jt * 4 + ks] = *(const uint4*)(BTb + 16384 + p * 8192 + jt * 4096 + off[ks]);
                }

        // pack this lane's sample config into 2 dwords (bit j = cfg column j)
        unsigned mbits = 0;
        {
            const int4* crow = (const int4*)(cfgG + (size_t)(s0 + s) * 64 + hi * 32);
            #pragma unroll
            for (int c = 0; c < 8; ++c) {
                int4 v = crow[c];
                mbits |= (unsigned)(v.x & 1) << (c * 4 + 0);
                mbits |= (unsigned)(v.y & 1) << (c * 4 + 1);
                mbits |= (unsigned)(v.z & 1) << (c * 4 + 2);
                mbits |= (unsigned)(v.w & 1) << (c * 4 + 3);
            }
        }
        unsigned other = __shfl_xor(mbits, 32);
        unsigned selLo = hi ? other : mbits;   // cfg cols 0..31
        unsigned selHi = hi ? mbits : other;   // cfg cols 32..63

        // env0 = left[cfg[:,0]] : lane (hi,s) fills groups hi*4..hi*4+3 of row s
        {
            const float* lp = leftG + (selLo & 1u) * 64 + hi * 32;
            #pragma unroll
            for (int gg = 0; gg < 4; ++gg) {
                float4 a = *(const float4*)(lp + gg * 8);
                float4 b = *(const float4*)(lp + gg * 8 + 4);
                uint4 w;
                w.x = (unsigned)f2bf(a.x) | ((unsigned)f2bf(a.y) << 16);
                w.y = (unsigned)f2bf(a.z) | ((unsigned)f2bf(a.w) << 16);
                w.z = (unsigned)f2bf(b.x) | ((unsigned)f2bf(b.y) << 16);
                w.w = (unsigned)f2bf(b.z) | ((unsigned)f2bf(b.w) << 16);
                int g = hi * 4 + gg;
                *(uint4*)((char*)env + s * 128 + ((g ^ e7) << 4)) = w;
            }
        }

        const f16v_t Z = {0.f};   // persistent zero C-operand (no per-step v_movs)
        for (int t = 0; t < NBULK; t += 2) {
            psi_phase(ra, t,     env, BTb, off, selLo, selHi, s, hi, e7, Z);
            psi_phase(rb, t + 1, env, BTb, off, selLo, selHi, s, hi, e7, Z);
        }

        // psi = env . right[:, cfg[:,63]]
        {
            int selL = (selHi >> 31) & 1;
            float psum = 0.f;
            #pragma unroll
            for (int gg = 0; gg < 4; ++gg) {
                int g = hi * 4 + gg;
                bf8_t e = *(const bf8_t*)((const char*)env + s * 128 + ((g ^ e7) << 4));
                #pragma unroll
                for (int j = 0; j < 8; ++j)
                    psum = fmaf(bf2f((unsigned short)e[j]), rightG[(g * 8 + j) * 2 + selL], psum);
            }
            psum += __shfl_xor(psum, 32);       // combine the two column halves
            float lp = logf(fmaxf(psum * psum, 1e-12f));
            if (hi) lp = 0.f;                   // lanes l and l^32 hold the same sample
            #pragma unroll
            for (int o = 1; o < 64; o <<= 1) lp += __shfl_xor(lp, o);
            if (lane == 0) atomicAdd(&wsF[0], lp);
        }
    } else {
        // ========== norm chain: fwd (bid 0) / bwd (bid 1), 31 sites, deferred rescale ==========
        unsigned short* Ebf = smem16;                    // 64 x SB (E, symmetric)
        unsigned short* St0 = Ebf + 64 * SB;
        unsigned short* St1 = St0 + 64 * SB;
        unsigned short* Ms0 = St1 + 64 * SB;             // 8192 (swizzled tile)
        unsigned short* Ms1 = Ms0 + 8192;
        float* wred = (float*)(Ms1 + 8192);              // [2][4]

        const int quad = lane >> 4;
        const int ln   = lane & 15;
        const bool fwd = (bid == 0);
        const unsigned short* srcbase = fwd ? BTg : MRg;
        {   // E0
            int i = tid >> 2, jq = tid & 3;
            for (int jj = 0; jj < 16; ++jj) {
                int j = jq * 16 + jj;
                float v;
                if (fwd) v = leftG[i] * leftG[j] + leftG[64 + i] * leftG[64 + j];
                else     v = rightG[i * 2] * rightG[j * 2] + rightG[i * 2 + 1] * rightG[j * 2 + 1];
                Ebf[i * SB + j] = f2bf(v);
            }
        }
        {   // prefetch site 0
            int st = fwd ? 0 : 61;
            const char* g = (const char*)(srcbase + (size_t)st * 8192);
            for (int c = 0; c < 4; ++c) {
                int chunk = wv * 4 + c;
                gload16(g + chunk * 1024 + (size_t)lane * 16, (char*)Ms0 + chunk * 1024);
            }
        }
        float lsum = 0.f;
        const int p   = wv >> 1;
        const int ntb = (wv & 1) * 2;
        const int mta = (wv >> 1) * 2;
        const int nta = (wv & 1) * 2;
        unsigned short* Stp = p ? St1 : St0;

        for (int k = 0; k < 31; ++k) {
            __syncthreads();   // Ms[k&1] resident; Ebf(k-1), wred(k-1) visible
            unsigned short* M = (k & 1) ? Ms1 : Ms0;
            if (k + 1 < 31) {
                int sn = fwd ? (k + 1) : (61 - (k + 1));
                const char* g = (const char*)(srcbase + (size_t)sn * 8192);
                char* l = (char*)((k & 1) ? Ms0 : Ms1);
                for (int c = 0; c < 4; ++c) {
                    int chunk = wv * 4 + c;
                    gload16(g + chunk * 1024 + (size_t)lane * 16, l + chunk * 1024);
                }
            }
            float inv = 1.f;
            if (k > 0) {
                const float* wp = wred + ((k - 1) & 1) * 4;
                float mm = fmaxf(fmaxf(wp[0], wp[1]), fmaxf(wp[2], wp[3]));
                float sc = fmaxf(mm, 1e-30f);
                inv = 1.f / sc;
                if (tid == 0) lsum += logf(sc);
            }
            // stage1: S_p = E * Op_p  (St stores transposed)
            {
                bf8_t Af2[4][2];
                #pragma unroll
                for (int mt = 0; mt < 4; ++mt)
                    #pragma unroll
                    for (int h = 0; h < 2; ++h)
                        Af2[mt][h] = *(const bf8_t*)(Ebf + (mt * 16 + ln) * SB + h * 32 + quad * 8);
                #pragma unroll
                for (int c = 0; c < 2; ++c) {
                    int nt = ntb + c;
                    int row = p * 64 + nt * 16 + ln;
                    bf8_t B0 = *(const bf8_t*)(M + row * 64 + (((0 + quad) ^ (ln & 7)) << 3));
                    bf8_t B1 = *(const bf8_t*)(M + row * 64 + (((4 + quad) ^ (ln & 7)) << 3));
                    #pragma unroll
                    for (int mt = 0; mt < 4; ++mt) {
                        f4_t a = {0.f, 0.f, 0.f, 0.f};
                        a = MFMA16(Af2[mt][0], B0, a);
                        a = MFMA16(Af2[mt][1], B1, a);
                        ushort4 pk;
                        pk.x = f2bf(a[0]); pk.y = f2bf(a[1]); pk.z = f2bf(a[2]); pk.w = f2bf(a[3]);
                        *(ushort4*)(Stp + (nt * 16 + ln) * SB + mt * 16 + quad * 4) = pk;
                    }
                }
            }
            // mid-step barrier: LDS-only drain — tile-(k+1) prefetch stays in flight
            // (the old __syncthreads forced vmcnt(0) here with only half a step of slack)
            asm volatile("s_waitcnt lgkmcnt(0)" ::: "memory");
            __builtin_amdgcn_s_barrier();
            __builtin_amdgcn_sched_barrier(0);
            // stage2: E' = sum_p Op_p-side * S_p ; scale by prev-site max; write Ebf
            {
                bf8_t Aw[2][2][2], Bw[2][2][2];
                #pragma unroll
                for (int pp = 0; pp < 2; ++pp)
                    #pragma unroll
                    for (int mi = 0; mi < 2; ++mi)
                        #pragma unroll
                        for (int h = 0; h < 2; ++h)
                            Aw[pp][mi][h] = *(const bf8_t*)(M + (pp * 64 + (mta + mi) * 16 + ln) * 64
                                                              + (((h * 4 + quad) ^ (ln & 7)) << 3));
                #pragma unroll
                for (int pp = 0; pp < 2; ++pp)
                    #pragma unroll
                    for (int ni = 0; ni < 2; ++ni)
                        #pragma unroll
                        for (int h = 0; h < 2; ++h)
                            Bw[pp][ni][h] = *(const bf8_t*)((pp ? St1 : St0)
                                                            + ((nta + ni) * 16 + ln) * SB + h * 32 + quad * 8);
                float mx = 0.f;
                #pragma unroll
                for (int mi = 0; mi < 2; ++mi)
                    #pragma unroll
                    for (int ni = 0; ni < 2; ++ni) {
                        f4_t a = {0.f, 0.f, 0.f, 0.f};
                        #pragma unroll
                        for (int pp = 0; pp < 2; ++pp)
                            #pragma unroll
                            for (int h = 0; h < 2; ++h)
                                a = MFMA16(Aw[pp][mi][h], Bw[pp][ni][h], a);
                        // E' is symmetric (E0=L^T L; step preserves symmetry), so write
                        // the TRANSPOSED element -> rows r are contiguous: one b64 store
                        // instead of 4 scalar ds_write_u16 (kills write bank conflicts)
                        float x0 = a[0] * inv, x1 = a[1] * inv, x2 = a[2] * inv, x3 = a[3] * inv;
                        mx = fmaxf(mx, fmaxf(fmaxf(fabsf(x0), fabsf(x1)), fmaxf(fabsf(x2), fabsf(x3))));
                        ushort4 pk;
                        pk.x = f2bf(x0); pk.y = f2bf(x1); pk.z = f2bf(x2); pk.w = f2bf(x3);
                        *(ushort4*)(Ebf + ((nta + ni) * 16 + ln) * SB + (mta + mi) * 16 + quad * 4) = pk;
                    }
                #pragma unroll
                for (int off2 = 32; off2 > 0; off2 >>= 1)
                    mx = fmaxf(mx, __shfl_xor(mx, off2));
                if (lane == 0) wred[(k & 1) * 4 + wv] = mx;
            }
        }
        __syncthreads();
        float* dst = wsF + (fwd ? WS_E_OFF : WS_B_OFF);
        for (int c = 0; c < 16; ++c) {
            int idx = tid + c * 256;
            dst[idx] = bf2f(Ebf[(idx >> 6) * SB + (idx & 63)]);
        }
        if (tid == 0) wsF[fwd ? 1 : 2] = lsum;
    }
}

extern "C" __global__ void mps_finalize(const float* __restrict__ wsF, float* __restrict__ out)
{
    const int lane = threadIdx.x;  // 64 threads
    const float* E  = wsF + WS_E_OFF;
    const float* Bm = wsF + WS_B_OFF;
    float a = 0.f;
    #pragma unroll 8
    for (int j = 0; j < 64; ++j)
        a = fmaf(E[lane * 64 + j], Bm[lane * 64 + j], a);
    #pragma unroll
    for (int off = 32; off > 0; off >>= 1)
        a += __shfl_down(a, off);
    if (lane == 0) {
        const float z = fmaxf(a, 1e-30f);
        const float log_z = logf(z) + wsF[1] + wsF[2];
        out[0] = log_z - wsF[0] * (1.0f / 8192.0f);
    }
}

extern "C" void kernel_launch(void* const* d_in, const int* in_sizes, int n_in,
                              void* d_out, int out_size, void* d_ws, size_t ws_size,
                              hipStream_t stream)
{
    const int*   cfg   = (const int*)d_in[0];    // (8192, 64) int32
    const float* left  = (const float*)d_in[1];  // (2, 64)
    const float* bulk  = (const float*)d_in[2];  // (62, 64, 2, 64)
    const float* right = (const float*)d_in[3];  // (64, 2)
    float* wsF = (float*)d_ws;
    unsigned short* BTg = (unsigned short*)((char*)d_ws + WS_BT_OFF);
    unsigned short* MRg = (unsigned short*)((char*)d_ws + WS_MR_OFF);

    mps_precompute<<<dim3(62), dim3(256), 0, stream>>>(bulk, BTg, MRg, wsF);
    // blocks 0,1 = norm chains (long pole, dispatch first); 2..129 = psi
    // (64 samples each: waves 0,1 are independent barrier-free 32-sample chains)
    mps_main<<<dim3(130), dim3(256), 60480, stream>>>(cfg, left, right, wsF, BTg, MRg);
    mps_finalize<<<dim3(1), dim3(64), 0, stream>>>(wsF, (float*)d_out);
}